// Round 1
// 214.808 us; speedup vs baseline: 1.0104x; 1.0104x over previous
//
#include <hip/hip_runtime.h>
#include <hip/hip_fp16.h>

#define N_NODES 100000
#define N_EDGES 1600000
#define D 64

#define BSHIFT 8
#define BUCK_N 256                      // nodes per bucket
#define NBUCK 391                       // ceil(100000/256)
#define EPB 4096                        // edges per phase-A block
#define NBLKA 391                       // ceil(1.6e6/4096)
#define SCAN_N (NBUCK * NBLKA)          // 152881
#define SCAN_B1 ((SCAN_N + 255) / 256)  // 598
#define A4_CAP 6144                     // bucket segment cap (mean 4096, sd 64)
#define X_OCTETS (N_NODES * D / 8)      // 800000
#define NBIN 2048                       // a4 bins: (node_local<<3)|(src>>14)
#define CVT_BLKS ((X_OCTETS + 2048 + 511) / 512)  // 1567

typedef _Float16 half8 __attribute__((ext_vector_type(8)));
typedef float floatx4 __attribute__((ext_vector_type(4)));

// ---------- fp32 -> fp16 convert helpers ----------

__device__ __forceinline__ uint4 pack8h(float4 a, float4 b) {
    __half2 h0, h1, h2, h3;
    h0.x = __float2half(a.x); h0.y = __float2half(a.y);
    h1.x = __float2half(a.z); h1.y = __float2half(a.w);
    h2.x = __float2half(b.x); h2.y = __float2half(b.y);
    h3.x = __float2half(b.z); h3.y = __float2half(b.w);
    uint4 pk;
    pk.x = *(unsigned int*)&h0; pk.y = *(unsigned int*)&h1;
    pk.z = *(unsigned int*)&h2; pk.w = *(unsigned int*)&h3;
    return pk;
}

// ---------- merged: Phase A1 histogram (blocks < NBLKA) + fp32->fp16 converts ----------

__global__ void pre_k(const float* __restrict__ x,
                      const float* __restrict__ W1l, const float* __restrict__ W1r,
                      const float* __restrict__ W2l, const float* __restrict__ W2r,
                      const int* __restrict__ dst, int* __restrict__ histG,
                      __half* __restrict__ x16,
                      __half* __restrict__ o1l, __half* __restrict__ o1r,
                      __half* __restrict__ o2l, __half* __restrict__ o2r) {
    __shared__ int hl[512];
    int t = threadIdx.x;  // 512
    if (blockIdx.x < NBLKA) {
        hl[t] = 0;
        __syncthreads();
        int base = blockIdx.x * EPB;
#pragma unroll
        for (int r = 0; r < 8; r++) {
            int idx = base + r * 512 + t;
            if (idx < N_EDGES) atomicAdd(&hl[dst[idx] >> BSHIFT], 1);
        }
        __syncthreads();
        if (t < NBUCK) histG[t * NBLKA + blockIdx.x] = hl[t];  // bucket-major
        return;
    }
    int i = (blockIdx.x - NBLKA) * 512 + t;
    const float* s;
    __half* d;
    int j;
    if (i < X_OCTETS) {
        s = x; d = x16; j = i * 8;
    } else {
        int k = i - X_OCTETS;
        if (k >= 2048) return;
        int arr = k >> 9;  // 512 octets per 4096-elem matrix
        j = (k & 511) * 8;
        s = (arr == 0) ? W1l : (arr == 1) ? W1r : (arr == 2) ? W2l : W2r;
        d = (arr == 0) ? o1l : (arr == 1) ? o1r : (arr == 2) ? o2l : o2r;
    }
    float4 a = *(const float4*)&s[j];
    float4 b = *(const float4*)&s[j + 4];
    *(uint4*)&d[j] = pack8h(a, b);
}

// ---------- scan of histG: block-local excl (scan1) + block-sum scan (scan2).
// Consumers add bsums[(idx>>8)-1] themselves (scan3 folded away).

__global__ void scan1_k(int* __restrict__ data, int* __restrict__ bsums, int n) {
    __shared__ int sm[256];
    int i = blockIdx.x * 256 + threadIdx.x;
    int v = (i < n) ? data[i] : 0;
    sm[threadIdx.x] = v;
    __syncthreads();
    for (int off = 1; off < 256; off <<= 1) {
        int t = (threadIdx.x >= off) ? sm[threadIdx.x - off] : 0;
        __syncthreads();
        sm[threadIdx.x] += t;
        __syncthreads();
    }
    if (i < n) data[i] = sm[threadIdx.x] - v;  // exclusive within block
    if (threadIdx.x == 255) bsums[blockIdx.x] = sm[255];
}

__global__ void scan2_k(int* __restrict__ bsums, int nb) {
    __shared__ int sm[1024];
    int v = (threadIdx.x < nb) ? bsums[threadIdx.x] : 0;
    sm[threadIdx.x] = v;
    __syncthreads();
    for (int off = 1; off < 1024; off <<= 1) {
        int t = (threadIdx.x >= off) ? sm[threadIdx.x - off] : 0;
        __syncthreads();
        sm[threadIdx.x] += t;
        __syncthreads();
    }
    if (threadIdx.x < nb) bsums[threadIdx.x] = sm[threadIdx.x];
}

__device__ __forceinline__ int hist_abs(const int* histG, const int* bsums, int idx) {
    int v = histG[idx];
    int blk = idx >> 8;
    if (blk > 0) v += bsums[blk - 1];
    return v;
}

// ---------- Phase A3: block-local counting sort, coalesced packed writes ----------
// epacked[g] = (dst_local << 17) | src

__global__ void a3_sort_k(const int* __restrict__ src, const int* __restrict__ dst,
                          const int* __restrict__ histG, const int* __restrict__ bsums,
                          unsigned int* __restrict__ epacked, int e) {
    __shared__ int hl[512];
    __shared__ int cur[512];
    __shared__ int sc[512];
    __shared__ int gbase[NBUCK];
    __shared__ unsigned int spk[EPB];
    __shared__ unsigned short sb[EPB];
    int t = threadIdx.x;  // 512
    int blk = blockIdx.x;
    int base = blk * EPB;

    hl[t] = 0;
    __syncthreads();

    int myd[8], mys[8];
#pragma unroll
    for (int r = 0; r < 8; r++) {
        int idx = base + r * 512 + t;
        if (idx < e) {
            myd[r] = dst[idx];
            mys[r] = src[idx];
            atomicAdd(&hl[myd[r] >> BSHIFT], 1);
        } else {
            myd[r] = -1; mys[r] = 0;
        }
    }
    __syncthreads();

    int v = hl[t];
    sc[t] = v;
    __syncthreads();
    for (int off = 1; off < 512; off <<= 1) {
        int tt = (t >= off) ? sc[t - off] : 0;
        __syncthreads();
        sc[t] += tt;
        __syncthreads();
    }
    int excl = sc[t] - v;
    hl[t] = excl;
    cur[t] = excl;
    if (t < NBUCK) gbase[t] = hist_abs(histG, bsums, t * NBLKA + blk);
    __syncthreads();

#pragma unroll
    for (int r = 0; r < 8; r++) {
        if (myd[r] >= 0) {
            int b = myd[r] >> BSHIFT;
            int dl = myd[r] & (BUCK_N - 1);
            int pos = atomicAdd(&cur[b], 1);
            spk[pos] = ((unsigned)dl << 17) | (unsigned)mys[r];
            sb[pos] = (unsigned short)b;
        }
    }
    __syncthreads();

    int cnt = e - base; if (cnt > EPB) cnt = EPB;
#pragma unroll
    for (int r = 0; r < 8; r++) {
        int i = r * 512 + t;
        if (i < cnt) {
            int b = sb[i];
            epacked[gbase[b] + (i - hl[b])] = spk[i];
        }
    }
}

// ---------- Phase A4 (once): per-bucket counting sort by (node, src-region) ----------
// 2048 bins = (node_local << 3) | (src >> 14). Within each node's edge list,
// edges come out ordered by source region (7 regions x 16384 nodes = 2 MB of
// fp16 rows each). All agg waves then sweep regions in near-lockstep, shrinking
// the instantaneous gather working set from 12.8 MB to ~2-4 MB (fits per-XCD
// 4 MB L2). row_ptr per node = start of its first bin.

__global__ void a4_nodesort_k(unsigned int* __restrict__ epk,
                              const int* __restrict__ histG, const int* __restrict__ bsums,
                              int* __restrict__ row_ptr) {
    __shared__ int sorted[A4_CAP];   // 24 KB
    __shared__ int hist[NBIN];       // 8 KB
    __shared__ int cur[NBIN];        // 8 KB
    __shared__ int sc[512];          // 2 KB
    int b = blockIdx.x;
    int t = threadIdx.x;  // 512

    int s0 = hist_abs(histG, bsums, b * NBLKA);
    int s1 = (b == NBUCK - 1) ? N_EDGES : hist_abs(histG, bsums, (b + 1) * NBLKA);
    int cnt = s1 - s0;
    if (cnt > A4_CAP) cnt = A4_CAP;

#pragma unroll
    for (int i = 0; i < NBIN / 512; i++) hist[t + i * 512] = 0;
    __syncthreads();

    unsigned int my[12];
    int mycnt = 0;
    for (int i = t; i < cnt; i += 512) {
        unsigned int p = epk[s0 + i];
        my[mycnt++] = p;
        atomicAdd(&hist[((p >> 17) << 3) | ((p & 0x1FFFFu) >> 14)], 1);
    }
    __syncthreads();

    // scan 2048 bins: thread t owns bins 4t..4t+3
    int b0 = t << 2;
    int h0 = hist[b0], h1 = hist[b0 + 1], h2 = hist[b0 + 2], h3 = hist[b0 + 3];
    int s = h0 + h1 + h2 + h3;
    sc[t] = s;
    __syncthreads();
    for (int off = 1; off < 512; off <<= 1) {
        int tt = (t >= off) ? sc[t - off] : 0;
        __syncthreads();
        sc[t] += tt;
        __syncthreads();
    }
    int base = sc[t] - s;  // exclusive across thread groups
    cur[b0] = base;
    cur[b0 + 1] = base + h0;
    cur[b0 + 2] = base + h0 + h1;
    cur[b0 + 3] = base + h0 + h1 + h2;
    __syncthreads();

    // row_ptr = start of node's first bin (read cur BEFORE atomics mutate it)
    if (t < 256) {
        int g = (b << BSHIFT) + t;
        if (g < N_NODES) row_ptr[g] = s0 + cur[t << 3];
    }
    __syncthreads();

    for (int i = 0; i < mycnt; i++) {
        unsigned int p = my[i];
        int pos = atomicAdd(&cur[((p >> 17) << 3) | ((p & 0x1FFFFu) >> 14)], 1);
        sorted[pos] = (int)(p & 0x1FFFF);
    }
    __syncthreads();

    for (int i = t; i < cnt; i += 512) epk[s0 + i] = (unsigned int)sorted[i];

    if (b == NBUCK - 1 && t == 0) row_ptr[N_NODES] = N_EDGES;
}

// ---------- aggregation: eighth-gather pull, PACKED fp16 accumulation ----------
// v_pk_add_f16 accumulate: 4 VALU ops/edge-lane. adj indices loaded ONE aligned
// dword per lane then broadcast within the 8-lane group via __shfl (LDS-permute
// pipe) — 9 VMEM inst per 8-edge burst instead of 16. Final mean in fp32.

__device__ __forceinline__ void addp(__half2* a, uint4 v) {
    const __half2* h = (const __half2*)&v;
    a[0] = __hadd2(a[0], h[0]);
    a[1] = __hadd2(a[1], h[1]);
    a[2] = __hadd2(a[2], h[2]);
    a[3] = __hadd2(a[3], h[3]);
}

__global__ void agg9_k(const __half* __restrict__ feat16,
                       const int* __restrict__ row_ptr,
                       const int* __restrict__ adj,
                       __half* __restrict__ mean16, int n) {
    int t = threadIdx.x;
    int lane = t & 63;
    int w = t >> 6;
    int node = blockIdx.x * 32 + w * 8 + (lane >> 3);
    if (node >= n) return;
    int fp = lane & 7;
    int gl = lane & 56;  // base lane of this 8-lane group
    const uint4* f16 = (const uint4*)feat16;  // 8 uint4 per 64-half row

    int beg = row_ptr[node];
    int end = row_ptr[node + 1];
    __half2 z; z.x = __float2half(0.f); z.y = z.x;
    __half2 aA[4] = {z, z, z, z};
    __half2 aB[4] = {z, z, z, z};

    int e = beg;
    for (; e + 7 < end; e += 8) {
        int am = adj[e + fp];  // lane fp owns edge e+fp: one aligned dword load
        int n0 = __shfl(am, gl + 0);
        int n1 = __shfl(am, gl + 1);
        int n2 = __shfl(am, gl + 2);
        int n3 = __shfl(am, gl + 3);
        int n4 = __shfl(am, gl + 4);
        int n5 = __shfl(am, gl + 5);
        int n6 = __shfl(am, gl + 6);
        int n7 = __shfl(am, gl + 7);
        uint4 v0 = f16[(size_t)n0 * 8 + fp];
        uint4 v1 = f16[(size_t)n1 * 8 + fp];
        uint4 v2 = f16[(size_t)n2 * 8 + fp];
        uint4 v3 = f16[(size_t)n3 * 8 + fp];
        uint4 v4 = f16[(size_t)n4 * 8 + fp];
        uint4 v5 = f16[(size_t)n5 * 8 + fp];
        uint4 v6 = f16[(size_t)n6 * 8 + fp];
        uint4 v7 = f16[(size_t)n7 * 8 + fp];
        addp(aA, v0); addp(aB, v1); addp(aA, v2); addp(aB, v3);
        addp(aA, v4); addp(aB, v5); addp(aA, v6); addp(aB, v7);
    }
    if (e + 3 < end) {
        uint4 v0 = f16[(size_t)adj[e] * 8 + fp];
        uint4 v1 = f16[(size_t)adj[e + 1] * 8 + fp];
        uint4 v2 = f16[(size_t)adj[e + 2] * 8 + fp];
        uint4 v3 = f16[(size_t)adj[e + 3] * 8 + fp];
        addp(aA, v0); addp(aB, v1); addp(aA, v2); addp(aB, v3);
        e += 4;
    }
    for (; e < end; e++) addp(aA, f16[(size_t)adj[e] * 8 + fp]);

    int dg = end - beg;
    float inv = (dg > 1) ? 1.0f / (float)dg : 1.0f;
    float2 s0 = __half22float2(aA[0]), s1 = __half22float2(aA[1]);
    float2 s2 = __half22float2(aA[2]), s3 = __half22float2(aA[3]);
    float2 t0 = __half22float2(aB[0]), t1 = __half22float2(aB[1]);
    float2 t2 = __half22float2(aB[2]), t3 = __half22float2(aB[3]);
    float4 o0, o1;
    o0.x = (s0.x + t0.x) * inv; o0.y = (s0.y + t0.y) * inv;
    o0.z = (s1.x + t1.x) * inv; o0.w = (s1.y + t1.y) * inv;
    o1.x = (s2.x + t2.x) * inv; o1.y = (s2.y + t2.y) * inv;
    o1.z = (s3.x + t3.x) * inv; o1.w = (s3.y + t3.y) * inv;
    *(uint4*)&mean16[(size_t)node * D + 8 * fp] = pack8h(o0, o1);
}

// ---------- linear via MFMA (fp16 in, fp32 accum) ----------
// Wave = 16-feature strip; A frags straight from row-major fp16 activations
// (one 16B load/lane, no LDS); B frags (weights) in 16 VGPRs, loaded once.
// C/D: col=lane&15, row=quad*4+reg (m89-verified).

#define NT 4  // node-tiles (of 16) per block

__global__ void gemm_mfma_k(const __half* __restrict__ Ap,   // mean16 [n][64]
                            const __half* __restrict__ Fp,   // feat16 [n][64]
                            const __half* __restrict__ Wl16, // [64][64]
                            const __half* __restrict__ Wr16,
                            const float* __restrict__ bl,
                            float* __restrict__ out32,       // nullable
                            __half* __restrict__ out16,      // nullable
                            int n, int do_relu) {
    int t = threadIdx.x;
    int wave = t >> 6;
    int lane = t & 63;
    int fcol = lane & 15;
    int quad = lane >> 4;
    int f = wave * 16 + fcol;

    half8 b0 = *(const half8*)(Wl16 + (size_t)f * 64 + quad * 8);
    half8 b1 = *(const half8*)(Wl16 + (size_t)f * 64 + 32 + quad * 8);
    half8 b2 = *(const half8*)(Wr16 + (size_t)f * 64 + quad * 8);
    half8 b3 = *(const half8*)(Wr16 + (size_t)f * 64 + 32 + quad * 8);
    float bias = bl[f];

    int ntiles = (n + 15) >> 4;
#pragma unroll
    for (int i = 0; i < NT; i++) {
        int tile = blockIdx.x * NT + i;
        if (tile >= ntiles) break;
        size_t arow = (size_t)(tile * 16 + fcol) * 64 + quad * 8;
        half8 a0 = *(const half8*)(Ap + arow);
        half8 a1 = *(const half8*)(Ap + arow + 32);
        half8 a2 = *(const half8*)(Fp + arow);
        half8 a3 = *(const half8*)(Fp + arow + 32);

        floatx4 acc = {0.f, 0.f, 0.f, 0.f};
        acc = __builtin_amdgcn_mfma_f32_16x16x32_f16(a0, b0, acc, 0, 0, 0);
        acc = __builtin_amdgcn_mfma_f32_16x16x32_f16(a1, b1, acc, 0, 0, 0);
        acc = __builtin_amdgcn_mfma_f32_16x16x32_f16(a2, b2, acc, 0, 0, 0);
        acc = __builtin_amdgcn_mfma_f32_16x16x32_f16(a3, b3, acc, 0, 0, 0);

#pragma unroll
        for (int r = 0; r < 4; r++) {
            int node = tile * 16 + quad * 4 + r;
            if (node >= n) break;
            float v = acc[r] + bias;
            if (do_relu) v = fmaxf(v, 0.f);
            if (out32) out32[(size_t)node * 64 + f] = v;
            if (out16) out16[(size_t)node * 64 + f] = __float2half(v);
        }
    }
}

extern "C" void kernel_launch(void* const* d_in, const int* in_sizes, int n_in,
                              void* d_out, int out_size, void* d_ws, size_t ws_size,
                              hipStream_t stream) {
    const float* x   = (const float*)d_in[0];
    const int*   ei  = (const int*)d_in[1];   // [2, E]: src then dst
    const float* W1l = (const float*)d_in[2];
    const float* b1l = (const float*)d_in[3];
    const float* W1r = (const float*)d_in[4];
    const float* W2l = (const float*)d_in[5];
    const float* b2l = (const float*)d_in[6];
    const float* W2r = (const float*)d_in[7];
    float* out = (float*)d_out;

    const int* src = ei;
    const int* dst = ei + N_EDGES;

    // workspace layout (~46 MB)
    __half* agg16 = (__half*)d_ws;                        // N*D
    __half* x16   = agg16 + (size_t)N_NODES * D;          // N*D
    __half* h16   = x16 + (size_t)N_NODES * D;            // N*D
    __half* w1l16 = h16 + (size_t)N_NODES * D;            // 4096
    __half* w1r16 = w1l16 + 4096;
    __half* w2l16 = w1r16 + 4096;
    __half* w2r16 = w2l16 + 4096;
    int*   histG = (int*)(w2r16 + 4096);                  // SCAN_N
    int*   bsums = histG + SCAN_N;                        // 1024
    int*   row_ptr = bsums + 1024;                        // N_NODES+1
    unsigned int* epk = (unsigned int*)(row_ptr + N_NODES + 2);  // N_EDGES

    // merged converts + bucket histogram
    pre_k<<<NBLKA + CVT_BLKS, 512, 0, stream>>>(x, W1l, W1r, W2l, W2r, dst, histG,
                                                x16, w1l16, w1r16, w2l16, w2r16);

    // build node-sorted (and src-region-sorted) adjacency, shared by both layers
    scan1_k<<<SCAN_B1, 256, 0, stream>>>(histG, bsums, SCAN_N);
    scan2_k<<<1, 1024, 0, stream>>>(bsums, SCAN_B1);
    a3_sort_k<<<NBLKA, 512, 0, stream>>>(src, dst, histG, bsums, epk, N_EDGES);
    a4_nodesort_k<<<NBUCK, 512, 0, stream>>>(epk, histG, bsums, row_ptr);

    int ab = (N_NODES + 31) / 32;                    // 3125
    int gmb = ((N_NODES + 15) / 16 + NT - 1) / NT;   // 1563

    // layer 1
    agg9_k<<<ab, 256, 0, stream>>>(x16, row_ptr, (const int*)epk, agg16, N_NODES);
    gemm_mfma_k<<<gmb, 256, 0, stream>>>(agg16, x16, w1l16, w1r16, b1l,
                                         (float*)nullptr, h16, N_NODES, 1);
    // layer 2
    agg9_k<<<ab, 256, 0, stream>>>(h16, row_ptr, (const int*)epk, agg16, N_NODES);
    gemm_mfma_k<<<gmb, 256, 0, stream>>>(agg16, h16, w2l16, w2r16, b2l,
                                         out, (__half*)nullptr, N_NODES, 0);
}

// Round 2
// 196.623 us; speedup vs baseline: 1.1039x; 1.0925x over previous
//
#include <hip/hip_runtime.h>
#include <hip/hip_fp16.h>

#define N_NODES 100000
#define N_EDGES 1600000
#define D 64

#define BSHIFT 8
#define BUCK_N 256                      // nodes per bucket
#define NBUCK 391                       // ceil(100000/256)
#define EPB 4096                        // edges per phase-A block
#define NBLKA 391                       // ceil(1.6e6/4096)
#define SCAN_N (NBUCK * NBLKA)          // 152881
#define SCAN_B1 ((SCAN_N + 255) / 256)  // 598
#define A4_CAP 6144                     // bucket segment cap (mean 4096, sd 64)
#define X_OCTETS (N_NODES * D / 8)      // 800000
#define CVT_BLKS ((X_OCTETS + 2048 + 511) / 512)  // 1567
#define AGB (N_NODES / 32)              // 3125 fused agg+gemm blocks (exact)

typedef _Float16 half8 __attribute__((ext_vector_type(8)));
typedef float floatx4 __attribute__((ext_vector_type(4)));

// ---------- fp32 -> fp16 convert helpers ----------

__device__ __forceinline__ uint4 pack8h(float4 a, float4 b) {
    __half2 h0, h1, h2, h3;
    h0.x = __float2half(a.x); h0.y = __float2half(a.y);
    h1.x = __float2half(a.z); h1.y = __float2half(a.w);
    h2.x = __float2half(b.x); h2.y = __float2half(b.y);
    h3.x = __float2half(b.z); h3.y = __float2half(b.w);
    uint4 pk;
    pk.x = *(unsigned int*)&h0; pk.y = *(unsigned int*)&h1;
    pk.z = *(unsigned int*)&h2; pk.w = *(unsigned int*)&h3;
    return pk;
}

// ---------- merged: Phase A1 histogram (blocks < NBLKA) + fp32->fp16 converts ----------

__global__ void pre_k(const float* __restrict__ x,
                      const float* __restrict__ W1l, const float* __restrict__ W1r,
                      const float* __restrict__ W2l, const float* __restrict__ W2r,
                      const int* __restrict__ dst, int* __restrict__ histG,
                      __half* __restrict__ x16,
                      __half* __restrict__ o1l, __half* __restrict__ o1r,
                      __half* __restrict__ o2l, __half* __restrict__ o2r) {
    __shared__ int hl[512];
    int t = threadIdx.x;  // 512
    if (blockIdx.x < NBLKA) {
        hl[t] = 0;
        __syncthreads();
        int base = blockIdx.x * EPB;
#pragma unroll
        for (int r = 0; r < 8; r++) {
            int idx = base + r * 512 + t;
            if (idx < N_EDGES) atomicAdd(&hl[dst[idx] >> BSHIFT], 1);
        }
        __syncthreads();
        if (t < NBUCK) histG[t * NBLKA + blockIdx.x] = hl[t];  // bucket-major
        return;
    }
    int i = (blockIdx.x - NBLKA) * 512 + t;
    const float* s;
    __half* d;
    int j;
    if (i < X_OCTETS) {
        s = x; d = x16; j = i * 8;
    } else {
        int k = i - X_OCTETS;
        if (k >= 2048) return;
        int arr = k >> 9;  // 512 octets per 4096-elem matrix
        j = (k & 511) * 8;
        s = (arr == 0) ? W1l : (arr == 1) ? W1r : (arr == 2) ? W2l : W2r;
        d = (arr == 0) ? o1l : (arr == 1) ? o1r : (arr == 2) ? o2l : o2r;
    }
    float4 a = *(const float4*)&s[j];
    float4 b = *(const float4*)&s[j + 4];
    *(uint4*)&d[j] = pack8h(a, b);
}

// ---------- scan of histG: block-local excl (scan1) + block-sum scan (scan2).
// Consumers add bsums[(idx>>8)-1] themselves (scan3 folded away).

__global__ void scan1_k(int* __restrict__ data, int* __restrict__ bsums, int n) {
    __shared__ int sm[256];
    int i = blockIdx.x * 256 + threadIdx.x;
    int v = (i < n) ? data[i] : 0;
    sm[threadIdx.x] = v;
    __syncthreads();
    for (int off = 1; off < 256; off <<= 1) {
        int t = (threadIdx.x >= off) ? sm[threadIdx.x - off] : 0;
        __syncthreads();
        sm[threadIdx.x] += t;
        __syncthreads();
    }
    if (i < n) data[i] = sm[threadIdx.x] - v;  // exclusive within block
    if (threadIdx.x == 255) bsums[blockIdx.x] = sm[255];
}

__global__ void scan2_k(int* __restrict__ bsums, int nb) {
    __shared__ int sm[1024];
    int v = (threadIdx.x < nb) ? bsums[threadIdx.x] : 0;
    sm[threadIdx.x] = v;
    __syncthreads();
    for (int off = 1; off < 1024; off <<= 1) {
        int t = (threadIdx.x >= off) ? sm[threadIdx.x - off] : 0;
        __syncthreads();
        sm[threadIdx.x] += t;
        __syncthreads();
    }
    if (threadIdx.x < nb) bsums[threadIdx.x] = sm[threadIdx.x];
}

__device__ __forceinline__ int hist_abs(const int* histG, const int* bsums, int idx) {
    int v = histG[idx];
    int blk = idx >> 8;
    if (blk > 0) v += bsums[blk - 1];
    return v;
}

// ---------- Phase A3: block-local counting sort, coalesced packed writes ----------
// epacked[g] = (dst_local << 17) | src

__global__ void a3_sort_k(const int* __restrict__ src, const int* __restrict__ dst,
                          const int* __restrict__ histG, const int* __restrict__ bsums,
                          unsigned int* __restrict__ epacked, int e) {
    __shared__ int hl[512];
    __shared__ int cur[512];
    __shared__ int sc[512];
    __shared__ int gbase[NBUCK];
    __shared__ unsigned int spk[EPB];
    __shared__ unsigned short sb[EPB];
    int t = threadIdx.x;  // 512
    int blk = blockIdx.x;
    int base = blk * EPB;

    hl[t] = 0;
    __syncthreads();

    int myd[8], mys[8];
#pragma unroll
    for (int r = 0; r < 8; r++) {
        int idx = base + r * 512 + t;
        if (idx < e) {
            myd[r] = dst[idx];
            mys[r] = src[idx];
            atomicAdd(&hl[myd[r] >> BSHIFT], 1);
        } else {
            myd[r] = -1; mys[r] = 0;
        }
    }
    __syncthreads();

    int v = hl[t];
    sc[t] = v;
    __syncthreads();
    for (int off = 1; off < 512; off <<= 1) {
        int tt = (t >= off) ? sc[t - off] : 0;
        __syncthreads();
        sc[t] += tt;
        __syncthreads();
    }
    int excl = sc[t] - v;
    hl[t] = excl;
    cur[t] = excl;
    if (t < NBUCK) gbase[t] = hist_abs(histG, bsums, t * NBLKA + blk);
    __syncthreads();

#pragma unroll
    for (int r = 0; r < 8; r++) {
        if (myd[r] >= 0) {
            int b = myd[r] >> BSHIFT;
            int dl = myd[r] & (BUCK_N - 1);
            int pos = atomicAdd(&cur[b], 1);
            spk[pos] = ((unsigned)dl << 17) | (unsigned)mys[r];
            sb[pos] = (unsigned short)b;
        }
    }
    __syncthreads();

    int cnt = e - base; if (cnt > EPB) cnt = EPB;
#pragma unroll
    for (int r = 0; r < 8; r++) {
        int i = r * 512 + t;
        if (i < cnt) {
            int b = sb[i];
            epacked[gbase[b] + (i - hl[b])] = spk[i];
        }
    }
}

// ---------- Phase A4 (once): per-bucket counting sort by node, in place ----------
// (256 bins: the 2048-bin src-region variant was measured neutral — blocks
// progress independently so region phasing cannot localize the working set.)

__global__ void a4_nodesort_k(unsigned int* __restrict__ epk,
                              const int* __restrict__ histG, const int* __restrict__ bsums,
                              int* __restrict__ row_ptr) {
    __shared__ int sorted[A4_CAP];
    __shared__ int hist[256];
    __shared__ int cur[256];
    __shared__ int sc[512];
    int b = blockIdx.x;
    int t = threadIdx.x;  // 512

    int s0 = hist_abs(histG, bsums, b * NBLKA);
    int s1 = (b == NBUCK - 1) ? N_EDGES : hist_abs(histG, bsums, (b + 1) * NBLKA);
    int cnt = s1 - s0;
    if (cnt > A4_CAP) cnt = A4_CAP;

    if (t < 256) hist[t] = 0;
    __syncthreads();

    unsigned int my[12];
    int mycnt = 0;
    for (int i = t; i < cnt; i += 512) {
        unsigned int p = epk[s0 + i];
        my[mycnt++] = p;
        atomicAdd(&hist[p >> 17], 1);
    }
    __syncthreads();

    int v = (t < 256) ? hist[t] : 0;
    sc[t] = v;
    __syncthreads();
    for (int off = 1; off < 512; off <<= 1) {
        int tt = (t >= off) ? sc[t - off] : 0;
        __syncthreads();
        sc[t] += tt;
        __syncthreads();
    }
    int start = sc[t] - v;
    if (t < 256) cur[t] = start;
    __syncthreads();

    for (int i = 0; i < mycnt; i++) {
        unsigned int p = my[i];
        int pos = atomicAdd(&cur[p >> 17], 1);
        sorted[pos] = (int)(p & 0x1FFFF);
    }
    __syncthreads();

    for (int i = t; i < cnt; i += 512) epk[s0 + i] = (unsigned int)sorted[i];

    if (t < 256) {
        int g = (b << BSHIFT) + t;
        if (g < N_NODES) row_ptr[g] = s0 + start;
    }
    if (b == NBUCK - 1 && t == 0) row_ptr[N_NODES] = N_EDGES;
}

// ---------- FUSED aggregation + linear (per layer, one kernel) ----------
// Block = 256 threads = 32 nodes (N_NODES = 3125*32 exactly, no tail).
// Phase 1 (agg): 8-lane groups gather+accumulate packed fp16, compute fp32
// mean, pack to fp16 into a 4 KB LDS tile (XOR-swizzled 16B chunks so the
// MFMA-phase read is bank-even). Phase 2 (gemm): each wave owns a 16-feature
// strip; A-frags for lin_l come from the LDS mean tile, A-frags for lin_r
// straight from global feat16 rows; B-frags in 16 VGPRs loaded once.
// Numerics identical to the split version (same fp32->fp16 pack point).

__device__ __forceinline__ void addp(__half2* a, uint4 v) {
    const __half2* h = (const __half2*)&v;
    a[0] = __hadd2(a[0], h[0]);
    a[1] = __hadd2(a[1], h[1]);
    a[2] = __hadd2(a[2], h[2]);
    a[3] = __hadd2(a[3], h[3]);
}

__global__ void agg_gemm_k(const __half* __restrict__ feat16,  // gather table == Fp
                           const int* __restrict__ row_ptr,
                           const int* __restrict__ adj,
                           const __half* __restrict__ Wl16,    // [64][64]
                           const __half* __restrict__ Wr16,
                           const float* __restrict__ bl,
                           float* __restrict__ out32,          // nullable
                           __half* __restrict__ out16,         // nullable
                           int do_relu) {
    __shared__ __half mt[32 * 64];  // mean tile, chunk-swizzled
    int t = threadIdx.x;
    int lane = t & 63;
    int w = t >> 6;
    int fp = lane & 7;
    int gl = lane & 56;             // base lane of 8-lane group
    int nloc = w * 8 + (lane >> 3); // 0..31
    int node = blockIdx.x * 32 + nloc;
    const uint4* f16 = (const uint4*)feat16;

    // B-frags + bias (latency hides under the gather loop)
    int fcol = lane & 15;
    int quad = lane >> 4;
    int f = w * 16 + fcol;
    half8 b0 = *(const half8*)(Wl16 + (size_t)f * 64 + quad * 8);
    half8 b1 = *(const half8*)(Wl16 + (size_t)f * 64 + 32 + quad * 8);
    half8 b2 = *(const half8*)(Wr16 + (size_t)f * 64 + quad * 8);
    half8 b3 = *(const half8*)(Wr16 + (size_t)f * 64 + 32 + quad * 8);
    float bias = bl[f];

    // ---- phase 1: mean aggregation ----
    int beg = row_ptr[node];
    int end = row_ptr[node + 1];
    __half2 z; z.x = __float2half(0.f); z.y = z.x;
    __half2 aA[4] = {z, z, z, z};
    __half2 aB[4] = {z, z, z, z};

    int e = beg;
    for (; e + 7 < end; e += 8) {
        int am = adj[e + fp];  // lane fp owns edge e+fp: one aligned dword load
        int n0 = __shfl(am, gl + 0);
        int n1 = __shfl(am, gl + 1);
        int n2 = __shfl(am, gl + 2);
        int n3 = __shfl(am, gl + 3);
        int n4 = __shfl(am, gl + 4);
        int n5 = __shfl(am, gl + 5);
        int n6 = __shfl(am, gl + 6);
        int n7 = __shfl(am, gl + 7);
        uint4 v0 = f16[(size_t)n0 * 8 + fp];
        uint4 v1 = f16[(size_t)n1 * 8 + fp];
        uint4 v2 = f16[(size_t)n2 * 8 + fp];
        uint4 v3 = f16[(size_t)n3 * 8 + fp];
        uint4 v4 = f16[(size_t)n4 * 8 + fp];
        uint4 v5 = f16[(size_t)n5 * 8 + fp];
        uint4 v6 = f16[(size_t)n6 * 8 + fp];
        uint4 v7 = f16[(size_t)n7 * 8 + fp];
        addp(aA, v0); addp(aB, v1); addp(aA, v2); addp(aB, v3);
        addp(aA, v4); addp(aB, v5); addp(aA, v6); addp(aB, v7);
    }
    if (e + 3 < end) {
        uint4 v0 = f16[(size_t)adj[e] * 8 + fp];
        uint4 v1 = f16[(size_t)adj[e + 1] * 8 + fp];
        uint4 v2 = f16[(size_t)adj[e + 2] * 8 + fp];
        uint4 v3 = f16[(size_t)adj[e + 3] * 8 + fp];
        addp(aA, v0); addp(aB, v1); addp(aA, v2); addp(aB, v3);
        e += 4;
    }
    for (; e < end; e++) addp(aA, f16[(size_t)adj[e] * 8 + fp]);

    int dg = end - beg;
    float inv = (dg > 1) ? 1.0f / (float)dg : 1.0f;
    float2 s0 = __half22float2(aA[0]), s1 = __half22float2(aA[1]);
    float2 s2 = __half22float2(aA[2]), s3 = __half22float2(aA[3]);
    float2 t0 = __half22float2(aB[0]), t1 = __half22float2(aB[1]);
    float2 t2 = __half22float2(aB[2]), t3 = __half22float2(aB[3]);
    float4 o0, o1;
    o0.x = (s0.x + t0.x) * inv; o0.y = (s0.y + t0.y) * inv;
    o0.z = (s1.x + t1.x) * inv; o0.w = (s1.y + t1.y) * inv;
    o1.x = (s2.x + t2.x) * inv; o1.y = (s2.y + t2.y) * inv;
    o1.z = (s3.x + t3.x) * inv; o1.w = (s3.y + t3.y) * inv;
    *(uint4*)&mt[(size_t)nloc * 64 + 8 * (fp ^ (nloc & 7))] = pack8h(o0, o1);
    __syncthreads();

    // ---- phase 2: out = mean @ Wl^T + bl + feat @ Wr^T ----
#pragma unroll
    for (int tile = 0; tile < 2; tile++) {
        int row = tile * 16 + fcol;
        half8 a0 = *(const half8*)&mt[(size_t)row * 64 + 8 * (quad ^ (row & 7))];
        half8 a1 = *(const half8*)&mt[(size_t)row * 64 + 8 * ((4 + quad) ^ (row & 7))];
        size_t frow = ((size_t)blockIdx.x * 32 + row) * 64 + quad * 8;
        half8 a2 = *(const half8*)(feat16 + frow);
        half8 a3 = *(const half8*)(feat16 + frow + 32);

        floatx4 acc = {0.f, 0.f, 0.f, 0.f};
        acc = __builtin_amdgcn_mfma_f32_16x16x32_f16(a0, b0, acc, 0, 0, 0);
        acc = __builtin_amdgcn_mfma_f32_16x16x32_f16(a1, b1, acc, 0, 0, 0);
        acc = __builtin_amdgcn_mfma_f32_16x16x32_f16(a2, b2, acc, 0, 0, 0);
        acc = __builtin_amdgcn_mfma_f32_16x16x32_f16(a3, b3, acc, 0, 0, 0);

#pragma unroll
        for (int r = 0; r < 4; r++) {
            int node2 = blockIdx.x * 32 + tile * 16 + quad * 4 + r;
            float v = acc[r] + bias;
            if (do_relu) v = fmaxf(v, 0.f);
            if (out32) out32[(size_t)node2 * 64 + f] = v;
            if (out16) out16[(size_t)node2 * 64 + f] = __float2half(v);
        }
    }
}

extern "C" void kernel_launch(void* const* d_in, const int* in_sizes, int n_in,
                              void* d_out, int out_size, void* d_ws, size_t ws_size,
                              hipStream_t stream) {
    const float* x   = (const float*)d_in[0];
    const int*   ei  = (const int*)d_in[1];   // [2, E]: src then dst
    const float* W1l = (const float*)d_in[2];
    const float* b1l = (const float*)d_in[3];
    const float* W1r = (const float*)d_in[4];
    const float* W2l = (const float*)d_in[5];
    const float* b2l = (const float*)d_in[6];
    const float* W2r = (const float*)d_in[7];
    float* out = (float*)d_out;

    const int* src = ei;
    const int* dst = ei + N_EDGES;

    // workspace layout (~33 MB)
    __half* x16   = (__half*)d_ws;                        // N*D
    __half* h16   = x16 + (size_t)N_NODES * D;            // N*D
    __half* w1l16 = h16 + (size_t)N_NODES * D;            // 4096
    __half* w1r16 = w1l16 + 4096;
    __half* w2l16 = w1r16 + 4096;
    __half* w2r16 = w2l16 + 4096;
    int*   histG = (int*)(w2r16 + 4096);                  // SCAN_N
    int*   bsums = histG + SCAN_N;                        // 1024
    int*   row_ptr = bsums + 1024;                        // N_NODES+1
    unsigned int* epk = (unsigned int*)(row_ptr + N_NODES + 2);  // N_EDGES

    // merged converts + bucket histogram
    pre_k<<<NBLKA + CVT_BLKS, 512, 0, stream>>>(x, W1l, W1r, W2l, W2r, dst, histG,
                                                x16, w1l16, w1r16, w2l16, w2r16);

    // build node-sorted adjacency (shared by both layers)
    scan1_k<<<SCAN_B1, 256, 0, stream>>>(histG, bsums, SCAN_N);
    scan2_k<<<1, 1024, 0, stream>>>(bsums, SCAN_B1);
    a3_sort_k<<<NBLKA, 512, 0, stream>>>(src, dst, histG, bsums, epk, N_EDGES);
    a4_nodesort_k<<<NBUCK, 512, 0, stream>>>(epk, histG, bsums, row_ptr);

    // layer 1: agg(x16) -> h16 (relu)
    agg_gemm_k<<<AGB, 256, 0, stream>>>(x16, row_ptr, (const int*)epk,
                                        w1l16, w1r16, b1l,
                                        (float*)nullptr, h16, 1);
    // layer 2: agg(h16) -> out (fp32)
    agg_gemm_k<<<AGB, 256, 0, stream>>>(h16, row_ptr, (const int*)epk,
                                        w2l16, w2r16, b2l,
                                        out, (__half*)nullptr, 0);
}